// Round 2
// baseline (641.313 us; speedup 1.0000x reference)
//
#include <hip/hip_runtime.h>
#include <math.h>

#define D    256   // input feature dim
#define BLK  256   // threads per block == samples per block
#define CH   32    // k-elements per staged chunk
#define NCH  (D/CH)

struct C2 { float x, y; };

// RY(t): [[c,-s],[s,c]] with c=cos(t/2), s=sin(t/2), applied on qubit mask m
__device__ __forceinline__ void gate_ry(C2 st[16], const int m, float c, float s) {
#pragma unroll
  for (int i = 0; i < 16; ++i) {
    if (i & m) continue;
    const int i1 = i | m;
    C2 a0 = st[i], a1 = st[i1];
    st[i].x  = c*a0.x - s*a1.x;  st[i].y  = c*a0.y - s*a1.y;
    st[i1].x = s*a0.x + c*a1.x;  st[i1].y = s*a0.y + c*a1.y;
  }
}

// RZ(t): diag(e^{-it/2}, e^{+it/2}); c=cos(t/2), s=sin(t/2)
__device__ __forceinline__ void gate_rz(C2 st[16], const int m, float c, float s) {
#pragma unroll
  for (int i = 0; i < 16; ++i) {
    C2 a = st[i];
    if (i & m) { st[i].x = a.x*c - a.y*s; st[i].y = a.y*c + a.x*s; }
    else       { st[i].x = a.x*c + a.y*s; st[i].y = a.y*c - a.x*s; }
  }
}

__global__ __launch_bounds__(BLK) void qhead_kernel(
    const float4* __restrict__ x4,
    const float*  __restrict__ w_proj,
    const float*  __restrict__ b_proj,
    const float*  __restrict__ qw,      // [2,4,2]
    const float*  __restrict__ w_h,     // [16,4]
    const float*  __restrict__ b_h,     // [16]
    const float*  __restrict__ w_out,   // [10,16]
    const float*  __restrict__ b_out,   // [10]
    float*        __restrict__ out)     // [B,10]
{
  __shared__ float4 wpT[D];            // wpT[k] = {w_proj[0][k], w1[k], w2[k], w3[k]}
  __shared__ float  xt[CH][BLK + 1];   // transposed x chunk: [k][sample], +1 pad

  const int tid = threadIdx.x;
  const long s0 = (long)blockIdx.x * BLK;
  const long xbase = s0 * (D / 4);     // in float4 units

  // stage transposed w_proj (one-time)
  wpT[tid] = make_float4(w_proj[tid], w_proj[D + tid], w_proj[2*D + tid], w_proj[3*D + tid]);

  // ---- projection: acc[j] = x[s] . w_proj[j] ----
  float4 v[8];
#pragma unroll
  for (int i = 0; i < 8; ++i) {        // prologue: chunk 0
    const int idx = i * BLK + tid;
    const int s = idx >> 3, k4 = idx & 7;
    v[i] = x4[xbase + (long)s * (D/4) + k4];
  }
  float4 acc = make_float4(0.f, 0.f, 0.f, 0.f);
#pragma unroll
  for (int c = 0; c < NCH; ++c) {
    __syncthreads();                   // previous chunk's reads done (wpT ready at c==0)
#pragma unroll
    for (int i = 0; i < 8; ++i) {      // transpose-write staged regs into LDS
      const int s  = i * 32 + (tid >> 3);
      const int kk = (tid & 7) * 4;
      xt[kk + 0][s] = v[i].x; xt[kk + 1][s] = v[i].y;
      xt[kk + 2][s] = v[i].z; xt[kk + 3][s] = v[i].w;
    }
    __syncthreads();
    if (c + 1 < NCH) {                 // prefetch next chunk (hides under compute)
#pragma unroll
      for (int i = 0; i < 8; ++i) {
        const int idx = i * BLK + tid;
        const int s = idx >> 3, k4 = idx & 7;
        v[i] = x4[xbase + (long)s * (D/4) + (c + 1) * 8 + k4];
      }
    }
#pragma unroll
    for (int k = 0; k < CH; ++k) {
      const float  xv = xt[k][tid];
      const float4 w  = wpT[c * CH + k];
      acc.x += xv * w.x; acc.y += xv * w.y; acc.z += xv * w.z; acc.w += xv * w.w;
    }
  }

  const float PI_F = 3.14159265358979f;
  float ang[4];
  ang[0] = tanhf(acc.x + b_proj[0]) * PI_F;
  ang[1] = tanhf(acc.y + b_proj[1]) * PI_F;
  ang[2] = tanhf(acc.z + b_proj[2]) * PI_F;
  ang[3] = tanhf(acc.w + b_proj[3]) * PI_F;

  // ---- 4-qubit statevector sim, fully in registers ----
  float ch[4], sh[4], cf[4], sf[4];
#pragma unroll
  for (int w = 0; w < 4; ++w) {
    __sincosf(0.5f * ang[w], &sh[w], &ch[w]);  // sin/cos(a/2): RY(a) and RZ(a)
    __sincosf(ang[w], &sf[w], &cf[w]);         // sin/cos(a):   RZ(2a)
  }

  C2 st[16];
#pragma unroll
  for (int i = 0; i < 16; ++i) { st[i].x = 0.f; st[i].y = 0.f; }
  st[0].x = 1.f;

#pragma unroll
  for (int layer = 0; layer < 2; ++layer) {
#pragma unroll
    for (int w = 0; w < 4; ++w) {      // data-dependent gates
      gate_ry(st, 8 >> w, ch[w], sh[w]);
      if (layer == 0) gate_rz(st, 8 >> w, ch[w], sh[w]);   // t = a
      else            gate_rz(st, 8 >> w, cf[w], sf[w]);   // t = 2a
    }
#pragma unroll
    for (int w = 0; w < 4; ++w) {      // trained gates (uniform scalar loads)
      float cw, sw, cz, sz;
      __sincosf(0.5f * qw[(layer * 4 + w) * 2 + 0], &sw, &cw);
      __sincosf(0.5f * qw[(layer * 4 + w) * 2 + 1], &sz, &cz);
      gate_ry(st, 8 >> w, cw, sw);
      gate_rz(st, 8 >> w, cz, sz);
    }
#pragma unroll
    for (int w = 0; w < 3; ++w) {      // CNOT chain: pure register swaps
      const int mc = 8 >> w, mt = 4 >> w;
#pragma unroll
      for (int i = 0; i < 16; ++i) {
        if ((i & mc) && !(i & mt)) {
          C2 t2 = st[i]; st[i] = st[i | mt]; st[i | mt] = t2;
        }
      }
    }
  }

  // ---- <Z_w> expvals ----
  float z[4] = {0.f, 0.f, 0.f, 0.f};
#pragma unroll
  for (int i = 0; i < 16; ++i) {
    const float p = st[i].x * st[i].x + st[i].y * st[i].y;
#pragma unroll
    for (int w = 0; w < 4; ++w) z[w] += (i & (8 >> w)) ? -p : p;
  }

  // ---- MLP head (weights via uniform scalar loads) ----
  float outv[10];
  {
    float h[16];
#pragma unroll
    for (int j = 0; j < 16; ++j) {
      float a = b_h[j];
#pragma unroll
      for (int w = 0; w < 4; ++w) a += w_h[j * 4 + w] * z[w];
      h[j] = fmaxf(a, 0.f);
    }
#pragma unroll
    for (int o = 0; o < 10; ++o) {
      float a = b_out[o];
#pragma unroll
      for (int j = 0; j < 16; ++j) a += w_out[o * 16 + j] * h[j];
      outv[o] = a;
    }
  }

  // ---- coalesced output via LDS re-use ----
  __syncthreads();                     // all xt reads done
  float* outS = &xt[0][0];             // 32*257 floats >= 2560
#pragma unroll
  for (int o = 0; o < 10; ++o) outS[tid * 10 + o] = outv[o];
  __syncthreads();
  float* og = out + (long)blockIdx.x * (BLK * 10);
#pragma unroll
  for (int i = 0; i < 10; ++i) og[i * BLK + tid] = outS[i * BLK + tid];
}

extern "C" void kernel_launch(void* const* d_in, const int* in_sizes, int n_in,
                              void* d_out, int out_size, void* d_ws, size_t ws_size,
                              hipStream_t stream) {
  const int B = in_sizes[0] / D;       // 131072
  dim3 grid(B / BLK), block(BLK);
  qhead_kernel<<<grid, block, 0, stream>>>(
      (const float4*)d_in[0],
      (const float*)d_in[1], (const float*)d_in[2], (const float*)d_in[3],
      (const float*)d_in[4], (const float*)d_in[5], (const float*)d_in[6],
      (const float*)d_in[7], (float*)d_out);
}

// Round 3
// 211.108 us; speedup vs baseline: 3.0378x; 3.0378x over previous
//
#include <hip/hip_runtime.h>
#include <math.h>

#define D    256   // input feature dim
#define BLK  256   // threads per block == samples per block
#define CH   32    // k-elements per staged chunk
#define NCH  (D/CH)

struct C2 { float x, y; };

// RY(t): [[c,-s],[s,c]] with c=cos(t/2), s=sin(t/2), applied on qubit mask m
__device__ __forceinline__ void gate_ry(C2 st[16], const int m, float c, float s) {
#pragma unroll
  for (int i = 0; i < 16; ++i) {
    if (i & m) continue;
    const int i1 = i | m;
    C2 a0 = st[i], a1 = st[i1];
    st[i].x  = c*a0.x - s*a1.x;  st[i].y  = c*a0.y - s*a1.y;
    st[i1].x = s*a0.x + c*a1.x;  st[i1].y = s*a0.y + c*a1.y;
  }
}

// RZ(t): diag(e^{-it/2}, e^{+it/2}); c=cos(t/2), s=sin(t/2)
__device__ __forceinline__ void gate_rz(C2 st[16], const int m, float c, float s) {
#pragma unroll
  for (int i = 0; i < 16; ++i) {
    C2 a = st[i];
    if (i & m) { st[i].x = a.x*c - a.y*s; st[i].y = a.y*c + a.x*s; }
    else       { st[i].x = a.x*c + a.y*s; st[i].y = a.y*c - a.x*s; }
  }
}

// __launch_bounds__(256, 4): 4 waves/EU min -> VGPR cap 128 (live set ~100,
// should not spill). Round-2 failure mode was VGPR=256 + ~860MB scratch
// traffic from over-unrolling; unroll pragmas below are the fix.
__global__ __launch_bounds__(BLK, 4) void qhead_kernel(
    const float4* __restrict__ x4,
    const float*  __restrict__ w_proj,
    const float*  __restrict__ b_proj,
    const float*  __restrict__ qw,      // [2,4,2]
    const float*  __restrict__ w_h,     // [16,4]
    const float*  __restrict__ b_h,     // [16]
    const float*  __restrict__ w_out,   // [10,16]
    const float*  __restrict__ b_out,   // [10]
    float*        __restrict__ out)     // [B,10]
{
  __shared__ float4 wpT[D];            // wpT[k] = {w_proj[0][k], w1[k], w2[k], w3[k]}
  __shared__ float  xt[CH][BLK + 1];   // transposed x chunk: [k][sample], +1 pad

  const int tid = threadIdx.x;
  const long s0 = (long)blockIdx.x * BLK;
  const long xbase = s0 * (D / 4);     // in float4 units

  // stage transposed w_proj (one-time)
  wpT[tid] = make_float4(w_proj[tid], w_proj[D + tid], w_proj[2*D + tid], w_proj[3*D + tid]);

  // ---- projection: acc[j] = x[s] . w_proj[j] ----
  float4 v[8];
#pragma unroll
  for (int i = 0; i < 8; ++i) {        // prologue: chunk 0 (coalesced, 128B/8lanes)
    const int idx = i * BLK + tid;
    const int s = idx >> 3, k4 = idx & 7;
    v[i] = x4[xbase + (long)s * (D/4) + k4];
  }
  float4 acc = make_float4(0.f, 0.f, 0.f, 0.f);
#pragma unroll 1                       // KEEP ROLLED: one body copy, bounded live set
  for (int c = 0; c < NCH; ++c) {
    __syncthreads();                   // previous chunk's LDS reads done (wpT ready at c==0)
#pragma unroll
    for (int i = 0; i < 8; ++i) {      // transpose-write staged regs into LDS (<=2-way bank, free)
      const int s  = i * 32 + (tid >> 3);
      const int kk = (tid & 7) * 4;
      xt[kk + 0][s] = v[i].x; xt[kk + 1][s] = v[i].y;
      xt[kk + 2][s] = v[i].z; xt[kk + 3][s] = v[i].w;
    }
    __syncthreads();
    if (c + 1 < NCH) {                 // prefetch next chunk (hides under FMA loop)
#pragma unroll
      for (int i = 0; i < 8; ++i) {
        const int idx = i * BLK + tid;
        const int s = idx >> 3, k4 = idx & 7;
        v[i] = x4[xbase + (long)s * (D/4) + (c + 1) * 8 + k4];
      }
    }
#pragma unroll 8                       // cap in-flight wpT ds_read_b128 at 8 (32 VGPR)
    for (int k = 0; k < CH; ++k) {
      const float  xv = xt[k][tid];
      const float4 w  = wpT[c * CH + k];
      acc.x += xv * w.x; acc.y += xv * w.y; acc.z += xv * w.z; acc.w += xv * w.w;
    }
  }

  const float PI_F = 3.14159265358979f;
  float ang[4];
  ang[0] = tanhf(acc.x + b_proj[0]) * PI_F;
  ang[1] = tanhf(acc.y + b_proj[1]) * PI_F;
  ang[2] = tanhf(acc.z + b_proj[2]) * PI_F;
  ang[3] = tanhf(acc.w + b_proj[3]) * PI_F;

  // ---- 4-qubit statevector sim, fully in registers (static indices only) ----
  float ch[4], sh[4], cf[4], sf[4];
#pragma unroll
  for (int w = 0; w < 4; ++w) {
    __sincosf(0.5f * ang[w], &sh[w], &ch[w]);  // sin/cos(a/2): RY(a) and RZ(a)
    __sincosf(ang[w], &sf[w], &cf[w]);         // sin/cos(a):   RZ(2a)
  }

  C2 st[16];
#pragma unroll
  for (int i = 0; i < 16; ++i) { st[i].x = 0.f; st[i].y = 0.f; }
  st[0].x = 1.f;

#pragma unroll
  for (int layer = 0; layer < 2; ++layer) {
#pragma unroll
    for (int w = 0; w < 4; ++w) {      // data-dependent gates
      gate_ry(st, 8 >> w, ch[w], sh[w]);
      if (layer == 0) gate_rz(st, 8 >> w, ch[w], sh[w]);   // t = a
      else            gate_rz(st, 8 >> w, cf[w], sf[w]);   // t = 2a
    }
#pragma unroll
    for (int w = 0; w < 4; ++w) {      // trained gates (uniform scalar loads)
      float cw, sw, cz, sz;
      __sincosf(0.5f * qw[(layer * 4 + w) * 2 + 0], &sw, &cw);
      __sincosf(0.5f * qw[(layer * 4 + w) * 2 + 1], &sz, &cz);
      gate_ry(st, 8 >> w, cw, sw);
      gate_rz(st, 8 >> w, cz, sz);
    }
#pragma unroll
    for (int w = 0; w < 3; ++w) {      // CNOT chain: pure register swaps
      const int mc = 8 >> w, mt = 4 >> w;
#pragma unroll
      for (int i = 0; i < 16; ++i) {
        if ((i & mc) && !(i & mt)) {
          C2 t2 = st[i]; st[i] = st[i | mt]; st[i | mt] = t2;
        }
      }
    }
  }

  // ---- <Z_w> expvals ----
  float z[4] = {0.f, 0.f, 0.f, 0.f};
#pragma unroll
  for (int i = 0; i < 16; ++i) {
    const float p = st[i].x * st[i].x + st[i].y * st[i].y;
#pragma unroll
    for (int w = 0; w < 4; ++w) z[w] += (i & (8 >> w)) ? -p : p;
  }

  // ---- MLP head (weights via uniform scalar loads) ----
  float outv[10];
  {
    float h[16];
#pragma unroll
    for (int j = 0; j < 16; ++j) {
      float a = b_h[j];
#pragma unroll
      for (int w = 0; w < 4; ++w) a += w_h[j * 4 + w] * z[w];
      h[j] = fmaxf(a, 0.f);
    }
#pragma unroll
    for (int o = 0; o < 10; ++o) {
      float a = b_out[o];
#pragma unroll
      for (int j = 0; j < 16; ++j) a += w_out[o * 16 + j] * h[j];
      outv[o] = a;
    }
  }

  // ---- coalesced output via LDS re-use ----
  __syncthreads();                     // all xt reads done
  float* outS = &xt[0][0];             // 32*257 floats >= 2560
#pragma unroll
  for (int o = 0; o < 10; ++o) outS[tid * 10 + o] = outv[o];
  __syncthreads();
  float* og = out + (long)blockIdx.x * (BLK * 10);
#pragma unroll
  for (int i = 0; i < 10; ++i) og[i * BLK + tid] = outS[i * BLK + tid];
}

extern "C" void kernel_launch(void* const* d_in, const int* in_sizes, int n_in,
                              void* d_out, int out_size, void* d_ws, size_t ws_size,
                              hipStream_t stream) {
  const int B = in_sizes[0] / D;       // 131072
  dim3 grid(B / BLK), block(BLK);
  qhead_kernel<<<grid, block, 0, stream>>>(
      (const float4*)d_in[0],
      (const float*)d_in[1], (const float*)d_in[2], (const float*)d_in[3],
      (const float*)d_in[4], (const float*)d_in[5], (const float*)d_in[6],
      (const float*)d_in[7], (float*)d_out);
}

// Round 6
// 210.716 us; speedup vs baseline: 3.0435x; 1.0019x over previous
//
#include <hip/hip_runtime.h>
#include <math.h>

#define D    256   // input feature dim
#define BLK  64    // threads per block == samples per block == ONE wave
#define CH   32    // k-elements per staged chunk
#define NCH  (D/CH)

struct C2 { float x, y; };

// RY(t): [[c,-s],[s,c]] with c=cos(t/2), s=sin(t/2), applied on qubit mask m
__device__ __forceinline__ void gate_ry(C2 st[16], const int m, float c, float s) {
#pragma unroll
  for (int i = 0; i < 16; ++i) {
    if (i & m) continue;
    const int i1 = i | m;
    C2 a0 = st[i], a1 = st[i1];
    st[i].x  = c*a0.x - s*a1.x;  st[i].y  = c*a0.y - s*a1.y;
    st[i1].x = s*a0.x + c*a1.x;  st[i1].y = s*a0.y + c*a1.y;
  }
}

// RZ(t): diag(e^{-it/2}, e^{+it/2}); c=cos(t/2), s=sin(t/2)
__device__ __forceinline__ void gate_rz(C2 st[16], const int m, float c, float s) {
#pragma unroll
  for (int i = 0; i < 16; ++i) {
    C2 a = st[i];
    if (i & m) { st[i].x = a.x*c - a.y*s; st[i].y = a.y*c + a.x*s; }
    else       { st[i].x = a.x*c + a.y*s; st[i].y = a.y*c - a.x*s; }
  }
}

// 1-wave blocks: __syncthreads degrades to waitcnt (compiler knows max
// workgroup = 64 from launch_bounds), waves on a CU are fully decoupled.
// (64,4): 4 waves/EU -> 16 blocks/CU allowed, VGPR cap 128 (live ~100).
// Round-2 lesson: VGPR=256+spill from over-unroll; keep unroll pragmas.
__global__ __launch_bounds__(BLK, 4) void qhead_kernel(
    const float4* __restrict__ x4,
    const float*  __restrict__ w_proj,
    const float*  __restrict__ b_proj,
    const float*  __restrict__ qw,      // [2,4,2]
    const float*  __restrict__ w_h,     // [16,4]
    const float*  __restrict__ b_h,     // [16]
    const float*  __restrict__ w_out,   // [10,16]
    const float*  __restrict__ b_out,   // [10]
    float*        __restrict__ out)     // [B,10]
{
  __shared__ float4 wpT[D];           // wpT[k] = {w0[k], w1[k], w2[k], w3[k]}
  __shared__ float  xt[CH][BLK + 1];  // transposed x chunk: [k][sample]

  const int tid = threadIdx.x;
  const long s0 = (long)blockIdx.x * BLK;
  const long xbase = s0 * (D / 4);    // in float4 units

  // stage transposed w_proj (4 float4 per thread)
#pragma unroll
  for (int r = 0; r < 4; ++r) {
    const int k = r * BLK + tid;
    wpT[k] = make_float4(w_proj[k], w_proj[D + k], w_proj[2*D + k], w_proj[3*D + k]);
  }

  // ---- projection: acc[j] = x[s] . w_proj[j] ----
  // per chunk: 64 samples x 8 float4 = 512 float4; 8 per thread.
  // idx = i*64+tid -> sample s = i*8+(tid>>3), float4 col k4 = tid&7
  // (8 consecutive lanes read 128B contiguous of one row -> coalesced)
  float4 v[8];
#pragma unroll
  for (int i = 0; i < 8; ++i) {       // prologue: chunk 0
    const int s = i * 8 + (tid >> 3), k4 = tid & 7;
    v[i] = x4[xbase + (long)s * (D/4) + k4];
  }
  float4 acc = make_float4(0.f, 0.f, 0.f, 0.f);
#pragma unroll 1                      // KEEP ROLLED: bounded live set
  for (int c = 0; c < NCH; ++c) {
    __syncthreads();                  // prior chunk's xt reads done (1-wave: waitcnt only)
#pragma unroll
    for (int i = 0; i < 8; ++i) {     // transpose into LDS (2-way bank alias = free)
      const int s  = i * 8 + (tid >> 3);
      const int kk = (tid & 7) * 4;
      xt[kk + 0][s] = v[i].x; xt[kk + 1][s] = v[i].y;
      xt[kk + 2][s] = v[i].z; xt[kk + 3][s] = v[i].w;
    }
    __syncthreads();
    if (c + 1 < NCH) {                // prefetch next chunk (hides under FMA + other waves)
#pragma unroll
      for (int i = 0; i < 8; ++i) {
        const int s = i * 8 + (tid >> 3), k4 = tid & 7;
        v[i] = x4[xbase + (long)s * (D/4) + (c + 1) * 8 + k4];
      }
    }
#pragma unroll 8                      // cap in-flight wpT ds_read_b128 at 8
    for (int k = 0; k < CH; ++k) {
      const float  xv = xt[k][tid];
      const float4 w  = wpT[c * CH + k];
      acc.x += xv * w.x; acc.y += xv * w.y; acc.z += xv * w.z; acc.w += xv * w.w;
    }
  }

  const float PI_F = 3.14159265358979f;
  float ang[4];
  ang[0] = tanhf(acc.x + b_proj[0]) * PI_F;
  ang[1] = tanhf(acc.y + b_proj[1]) * PI_F;
  ang[2] = tanhf(acc.z + b_proj[2]) * PI_F;
  ang[3] = tanhf(acc.w + b_proj[3]) * PI_F;

  // ---- 4-qubit statevector sim, fully in registers (static indices only) ----
  float ch[4], sh[4], cf[4], sf[4];
#pragma unroll
  for (int w = 0; w < 4; ++w) {
    __sincosf(0.5f * ang[w], &sh[w], &ch[w]);  // sin/cos(a/2): RY(a) and RZ(a)
    __sincosf(ang[w], &sf[w], &cf[w]);         // sin/cos(a):   RZ(2a)
  }

  C2 st[16];
#pragma unroll
  for (int i = 0; i < 16; ++i) { st[i].x = 0.f; st[i].y = 0.f; }
  st[0].x = 1.f;

#pragma unroll
  for (int layer = 0; layer < 2; ++layer) {
#pragma unroll
    for (int w = 0; w < 4; ++w) {     // data-dependent gates
      gate_ry(st, 8 >> w, ch[w], sh[w]);
      if (layer == 0) gate_rz(st, 8 >> w, ch[w], sh[w]);   // t = a
      else            gate_rz(st, 8 >> w, cf[w], sf[w]);   // t = 2a
    }
#pragma unroll
    for (int w = 0; w < 4; ++w) {     // trained gates (uniform scalar loads)
      float cw, sw, cz, sz;
      __sincosf(0.5f * qw[(layer * 4 + w) * 2 + 0], &sw, &cw);
      __sincosf(0.5f * qw[(layer * 4 + w) * 2 + 1], &sz, &cz);
      gate_ry(st, 8 >> w, cw, sw);
      gate_rz(st, 8 >> w, cz, sz);
    }
#pragma unroll
    for (int w = 0; w < 3; ++w) {     // CNOT chain: pure register swaps
      const int mc = 8 >> w, mt = 4 >> w;
#pragma unroll
      for (int i = 0; i < 16; ++i) {
        if ((i & mc) && !(i & mt)) {
          C2 t2 = st[i]; st[i] = st[i | mt]; st[i | mt] = t2;
        }
      }
    }
  }

  // ---- <Z_w> expvals ----
  float z[4] = {0.f, 0.f, 0.f, 0.f};
#pragma unroll
  for (int i = 0; i < 16; ++i) {
    const float p = st[i].x * st[i].x + st[i].y * st[i].y;
#pragma unroll
    for (int w = 0; w < 4; ++w) z[w] += (i & (8 >> w)) ? -p : p;
  }

  // ---- MLP head (weights via uniform scalar loads) ----
  float outv[10];
  {
    float h[16];
#pragma unroll
    for (int j = 0; j < 16; ++j) {
      float a = b_h[j];
#pragma unroll
      for (int w = 0; w < 4; ++w) a += w_h[j * 4 + w] * z[w];
      h[j] = fmaxf(a, 0.f);
    }
#pragma unroll
    for (int o = 0; o < 10; ++o) {
      float a = b_out[o];
#pragma unroll
      for (int j = 0; j < 16; ++j) a += w_out[o * 16 + j] * h[j];
      outv[o] = a;
    }
  }

  // ---- coalesced output via LDS re-use (stride 11: coprime with 32 banks) ----
  __syncthreads();                    // all xt reads done
  float* outS = &xt[0][0];            // 32*65 = 2080 floats >= 64*11 = 704
#pragma unroll
  for (int o = 0; o < 10; ++o) outS[tid * 11 + o] = outv[o];
  __syncthreads();
  float* og = out + (long)blockIdx.x * (BLK * 10);
#pragma unroll
  for (int i = 0; i < 10; ++i) {      // 640 contiguous floats, 64/iter
    const int j = i * BLK + tid;
    og[j] = outS[(j / 10) * 11 + (j % 10)];
  }
}

extern "C" void kernel_launch(void* const* d_in, const int* in_sizes, int n_in,
                              void* d_out, int out_size, void* d_ws, size_t ws_size,
                              hipStream_t stream) {
  const int B = in_sizes[0] / D;      // 131072
  dim3 grid(B / BLK), block(BLK);
  qhead_kernel<<<grid, block, 0, stream>>>(
      (const float4*)d_in[0],
      (const float*)d_in[1], (const float*)d_in[2], (const float*)d_in[3],
      (const float*)d_in[4], (const float*)d_in[5], (const float*)d_in[6],
      (const float*)d_in[7], (float*)d_out);
}